// Round 9
// baseline (85.665 us; speedup 1.0000x reference)
//
#include <hip/hip_runtime.h>

#define G_ 20000
#define W_ 8
#define K_ 16
#define T_ 1500
#define B_ 256
#define D_ 2
#define BPT 2        // batch rows per thread (the packed axis)
#define TPB 128      // threads per block = B_/BPT; 2 waves; 1 group per block
#define PSTRIDE 308  // floats per packed group record (1232 B, 16B-aligned)

// transpose_feat tiles: ceil(1500/32)=47 x 256/32=8
#define TF_TX 47
#define TF_BLOCKS (TF_TX * 8)

typedef float v2f __attribute__((ext_vector_type(2)));

// ---------- fused prep kernel (unchanged from round 7) ----------
// Record layout (floats):
//   [0,16)    tf_idx*B_ (int bits)
//   [16,144)  W1t[k][w]   * log2e
//   [144,152) b1          * log2e
//   [152,280) Wmt[d][w][v]* scale*log2e
//   [280,296) bm[d][v]    * log2e
//   [296,304) Wf          * scale
//   [304]     bf ; [305,308) pad
__global__ __launch_bounds__(256) void prep_kernel(
    const float* __restrict__ feat,
    float* __restrict__ featT,
    const int*   __restrict__ tf_idx,
    const float* __restrict__ W1,
    const float* __restrict__ b1,
    const float* __restrict__ Wm,
    const float* __restrict__ bm,
    const float* __restrict__ Wf,
    const float* __restrict__ bf,
    float* __restrict__ pack)
{
    const int bid = blockIdx.x;
    const int tid = threadIdx.x;
    if (bid < TF_BLOCKS) {
        __shared__ float tile[32][33];
        int t0 = (bid % TF_TX) * 32;
        int b0 = (bid / TF_TX) * 32;
        int tx = tid & 31, ty = tid >> 5;      // (32,8)
        #pragma unroll
        for (int i = 0; i < 32; i += 8) {
            int bb = b0 + ty + i, tt = t0 + tx;
            if (tt < T_) tile[ty + i][tx] = feat[bb * T_ + tt];
        }
        __syncthreads();
        #pragma unroll
        for (int i = 0; i < 32; i += 8) {
            int tt = t0 + ty + i, bb = b0 + tx;
            if (tt < T_) featT[tt * B_ + bb] = tile[tx][ty + i];
        }
        return;
    }
    const int g = bid - TF_BLOCKS;
    const float LOG2E = 1.44269504088896340736f;
    const float SCALE = 1.0507009873554805f;
    float* rec = pack + (long)g * PSTRIDE;
    for (int j = tid; j < PSTRIDE; j += 256) {
        float v;
        if (j < 16) {
            v = __int_as_float(tf_idx[g * K_ + j] * B_);
        } else if (j < 144) {
            int r = j - 16, k = r >> 3, w = r & 7;
            v = LOG2E * W1[((long)g * W_ + w) * K_ + k];
        } else if (j < 152) {
            v = LOG2E * b1[g * W_ + (j - 144)];
        } else if (j < 280) {
            int r = j - 152, d = r >> 6, w = (r >> 3) & 7, vv = r & 7;
            v = SCALE * LOG2E * Wm[(((long)d * G_ + g) * W_ + vv) * W_ + w];
        } else if (j < 296) {
            int r = j - 280, d = r >> 3, vv = r & 7;
            v = LOG2E * bm[((long)d * G_ + g) * W_ + vv];
        } else if (j < 304) {
            v = SCALE * Wf[g * W_ + (j - 296)];
        } else if (j == 304) {
            v = bf[g];
        } else {
            v = 0.0f;
        }
        rec[j] = v;
    }
}

// outT (G,B) -> out (B,G), both sides coalesced via LDS tile.
__global__ void transpose_out(const float* __restrict__ in,
                              float* __restrict__ outp) {
    __shared__ float tile[32][33];
    int g0 = blockIdx.x * 32;
    int b0 = blockIdx.y * 32;
    int tx = threadIdx.x, ty = threadIdx.y;  // block (32,8)
    #pragma unroll
    for (int i = 0; i < 32; i += 8)
        tile[ty + i][tx] = in[(size_t)(g0 + ty + i) * B_ + b0 + tx];
    __syncthreads();
    #pragma unroll
    for (int i = 0; i < 32; i += 8)
        outp[(size_t)(b0 + ty + i) * G_ + g0 + tx] = tile[tx][ty + i];
}

// ---------- main kernel ----------

// Packed f32 FMA, weight broadcast from a uniform SGPR PAIR (64-bit scalar
// operand must be an even-aligned pair on gfx950 — single SGPR was the
// round-8 compile failure). op_sel/op_sel_hi pick which dword broadcasts.
// c.lo += w*x.lo ; c.hi += w*x.hi   where w = wpair.lo:
__device__ __forceinline__ void pk_fma_lo(v2f wpair, v2f x, v2f& c) {
    asm("v_pk_fma_f32 %0, %1, %2, %0 op_sel_hi:[0,1,1]"
        : "+v"(c) : "s"(wpair), "v"(x));
}
// ... where w = wpair.hi:
__device__ __forceinline__ void pk_fma_hi(v2f wpair, v2f x, v2f& c) {
    asm("v_pk_fma_f32 %0, %1, %2, %0 op_sel:[1,0,0] op_sel_hi:[1,1,1]"
        : "+v"(c) : "s"(wpair), "v"(x));
}
// F is a compile-time float offset into the record; lo/hi folds at compile.
#define PKFMA(F, x, c) do { \
    if ((F) & 1) pk_fma_hi(P2[(F) >> 1], (x), (c)); \
    else         pk_fma_lo(P2[(F) >> 1], (x), (c)); \
} while (0)

// u = log2e*z pair (over 2 batch rows); returns selu(z)/scale pair.
__device__ __forceinline__ v2f selu2(v2f u) {
    const float ALPHA = 1.6732632423543772f;
    const float LN2   = 0.6931471805599453f;
    v2f e;
    e.x = __builtin_amdgcn_exp2f(u.x);
    e.y = __builtin_amdgcn_exp2f(u.y);
    v2f m = e * ALPHA - ALPHA;
    v2f r;
    r.x = fmaf(fmaxf(u.x, 0.0f), LN2, fminf(m.x, 0.0f));
    r.y = fmaf(fmaxf(u.y, 0.0f), LN2, fminf(m.y, 0.0f));
    return r;
}

// 128 threads (2 waves), 1 group per block; thread owns batch rows
// {2*tid, 2*tid+1}, kept PACKED in v2f through the whole MLP.
// Weights are uniform SGPR pairs broadcast inside v_pk_fma_f32.
__global__ __launch_bounds__(TPB, 6) void decoder_pk(
    const float* __restrict__ featT,   // (T,B)
    const float* __restrict__ pack,    // (G,PSTRIDE)
    float* __restrict__ outT)          // (G,B)
{
    const int tid = threadIdx.x;
    const int b0  = BPT * tid;
    const int g   = blockIdx.x;
    const float* fb = featT + b0;

    const float* P    = pack + (long)g * PSTRIDE;
    const v2f*   P2   = (const v2f*)P;
    const int*   idxp = (const int*)P;            // [0,16): t*B_

    // coalesced float2 gathers: both batch rows in one dwordx2
    v2f xg[K_];
    #pragma unroll
    for (int k = 0; k < K_; ++k) {
        float2 t = *(const float2*)(fb + idxp[k]);
        xg[k].x = t.x; xg[k].y = t.y;
    }

    // layer 1: acc[w] over the batch pair; bias splat init
    v2f h[W_];
    #pragma unroll
    for (int w = 0; w < W_; ++w) {
        float bw = P[144 + w];
        h[w].x = bw; h[w].y = bw;
    }
    #pragma unroll
    for (int k = 0; k < K_; ++k) {
        v2f x = xg[k];
        #pragma unroll
        for (int w = 0; w < W_; ++w)
            PKFMA(16 + 8 * k + w, x, h[w]);
    }
    #pragma unroll
    for (int w = 0; w < W_; ++w) h[w] = selu2(h[w]);

    // mid layers: new[v] = sum_w h[w] * Wm'(v,w)
    #pragma unroll
    for (int d = 0; d < D_; ++d) {
        v2f m[W_];
        #pragma unroll
        for (int v = 0; v < W_; ++v) {
            float bv = P[280 + 8 * d + v];
            m[v].x = bv; m[v].y = bv;
        }
        #pragma unroll
        for (int w = 0; w < W_; ++w) {
            v2f hw = h[w];
            #pragma unroll
            for (int v = 0; v < W_; ++v)
                PKFMA(152 + 64 * d + 8 * w + v, hw, m[v]);
        }
        #pragma unroll
        for (int v = 0; v < W_; ++v) h[v] = selu2(m[v]);
    }

    // final dot: halves of s are the two batch outputs directly
    float bfv = P[304];
    v2f s; s.x = bfv; s.y = bfv;
    #pragma unroll
    for (int w = 0; w < W_; ++w)
        PKFMA(296 + w, h[w], s);

    // full-line coalesced store: 128 threads x 8B = 1KB contiguous per group
    *(float2*)(outT + (size_t)g * B_ + b0) = make_float2(s.x, s.y);
}

// ---------- fallbacks (small workspace) ----------
#define FGPB 4
__device__ __forceinline__ float selu_f(float x) {
    const float scale = 1.0507009873554805f;
    const float sa    = 1.7580993408473766f;
    float e   = __expf(x);
    float neg = fmaf(sa, e, -sa);
    return x > 0.0f ? scale * x : neg;
}
template<bool TRANSPOSED>
__global__ __launch_bounds__(256) void decoder_kernel(
    const float* __restrict__ featsrc, const int* __restrict__ tf_idx,
    const float* __restrict__ W1, const float* __restrict__ b1,
    const float* __restrict__ Wm, const float* __restrict__ bm,
    const float* __restrict__ Wf, const float* __restrict__ bf,
    float* __restrict__ out)
{
    const int b  = threadIdx.x;
    const int g0 = blockIdx.x * FGPB;
    float res[FGPB];
    #pragma unroll
    for (int gi = 0; gi < FGPB; ++gi) {
        const int g = g0 + gi;
        float xg[K_];
        #pragma unroll
        for (int k = 0; k < K_; ++k) {
            int t = tf_idx[g * K_ + k];
            xg[k] = TRANSPOSED ? featsrc[t * B_ + b] : featsrc[b * T_ + t];
        }
        float h[W_];
        #pragma unroll
        for (int w = 0; w < W_; ++w) {
            float acc = b1[g * W_ + w];
            #pragma unroll
            for (int k = 0; k < K_; ++k)
                acc = fmaf(xg[k], W1[(g * W_ + w) * K_ + k], acc);
            h[w] = selu_f(acc);
        }
        #pragma unroll
        for (int d = 0; d < D_; ++d) {
            const float* wmd = Wm + ((size_t)d * G_ + g) * (W_ * W_);
            const float* bmd = bm + ((size_t)d * G_ + g) * W_;
            float h2[W_];
            #pragma unroll
            for (int v = 0; v < W_; ++v) {
                float acc = bmd[v];
                #pragma unroll
                for (int w = 0; w < W_; ++w)
                    acc = fmaf(h[w], wmd[v * W_ + w], acc);
                h2[v] = selu_f(acc);
            }
            #pragma unroll
            for (int w = 0; w < W_; ++w) h[w] = h2[w];
        }
        float acc = bf[g];
        #pragma unroll
        for (int w = 0; w < W_; ++w)
            acc = fmaf(h[w], Wf[g * W_ + w], acc);
        res[gi] = acc;
    }
    float4* o = (float4*)(out + (size_t)b * G_ + g0);
    o[0] = make_float4(res[0], res[1], res[2], res[3]);
}

extern "C" void kernel_launch(void* const* d_in, const int* in_sizes, int n_in,
                              void* d_out, int out_size, void* d_ws, size_t ws_size,
                              hipStream_t stream) {
    const float* feat   = (const float*)d_in[0];
    const int*   tf_idx = (const int*)  d_in[1];
    const float* W1     = (const float*)d_in[2];
    const float* b1     = (const float*)d_in[3];
    const float* Wm     = (const float*)d_in[4];
    const float* bm     = (const float*)d_in[5];
    const float* Wf     = (const float*)d_in[6];
    const float* bf     = (const float*)d_in[7];
    float* out = (float*)d_out;

    const size_t featT_b = (size_t)T_ * B_ * sizeof(float);        // 1.536 MB
    const size_t pack_b  = (size_t)G_ * PSTRIDE * sizeof(float);   // 24.64 MB
    const size_t outT_b  = (size_t)G_ * B_ * sizeof(float);        // 20.48 MB

    if (ws_size >= featT_b + pack_b + outT_b) {
        float* featT = (float*)d_ws;
        float* packp = (float*)((char*)d_ws + featT_b);
        float* outT  = (float*)((char*)d_ws + featT_b + pack_b);

        hipLaunchKernelGGL(prep_kernel, dim3(TF_BLOCKS + G_), dim3(256), 0,
                           stream, feat, featT, tf_idx, W1, b1, Wm, bm, Wf, bf,
                           packp);

        hipLaunchKernelGGL(decoder_pk, dim3(G_), dim3(TPB), 0,
                           stream, featT, packp, outT);

        hipLaunchKernelGGL(transpose_out, dim3(G_ / 32, B_ / 32), dim3(32, 8), 0,
                           stream, outT, out);
    } else if (ws_size >= featT_b) {
        float* featT = (float*)d_ws;
        hipLaunchKernelGGL(prep_kernel, dim3(TF_BLOCKS), dim3(256), 0,
                           stream, feat, featT, tf_idx, W1, b1, Wm, bm, Wf, bf,
                           featT /*unused pack*/);
        hipLaunchKernelGGL((decoder_kernel<true>), dim3(G_ / FGPB), dim3(B_), 0,
                           stream, featT, tf_idx, W1, b1, Wm, bm, Wf, bf, out);
    } else {
        hipLaunchKernelGGL((decoder_kernel<false>), dim3(G_ / FGPB), dim3(B_), 0,
                           stream, feat, tf_idx, W1, b1, Wm, bm, Wf, bf, out);
    }
}

// Round 11
// 76.036 us; speedup vs baseline: 1.1266x; 1.1266x over previous
//
#include <hip/hip_runtime.h>
#include <hip/hip_fp16.h>

#define G_ 20000
#define W_ 8
#define K_ 16
#define T_ 1500
#define B_ 256
#define D_ 2
#define BPT 2        // batch rows per thread
#define TPB 128      // threads per block = B_/BPT; 2 waves; 1 group per block
#define PSTRIDE 176  // u32 slots per packed group record (704 B, 16B-aligned)

// transpose_feat tiles: ceil(1500/32)=47 x 256/32=8
#define TF_TX 47
#define TF_BLOCKS (TF_TX * 8)

// Use the builtin's own return type so cvt_pkrtz / fdot2 operand types unify
// (round-10 fail: _Float16 vector vs __fp16 vector are incompatible in clang).
typedef decltype(__builtin_amdgcn_cvt_pkrtz(0.0f, 0.0f)) v2h;

__device__ __forceinline__ unsigned pack_h2(float lo, float hi) {
    __half l = __float2half(lo), h = __float2half(hi);   // RTE
    return ((unsigned)__half_as_ushort(h) << 16) | __half_as_ushort(l);
}
__device__ __forceinline__ v2h as_v2h(unsigned u) {
    v2h r; __builtin_memcpy(&r, &u, 4); return r;
}

// ---------- fused prep kernel ----------
// blocks [0, TF_BLOCKS): feat (B,T) -> featT (T,B)
// blocks [TF_BLOCKS, +G_): pack ONE group record each.
// Record layout (u32 slots):
//   [0,16)    tf_idx*B_ (int)
//   [16,80)   W1 f16 pairs over k:  16 + 8*k2 + w   = h2(LOG2E*W1[g][w][2k2], ..2k2+1)
//   [80,144)  Wm f16 pairs over w:  80 + 32*d + 8*w2 + v (scaled by SCALE*LOG2E)
//   [144,148) Wf f16 pairs over w:  144 + w2 (scaled by SCALE)
//   [148,156) b1 f32 * LOG2E
//   [156,172) bm f32 * LOG2E: 156 + 8*d + v
//   [172]     bf f32 ; [173,176) pad
__global__ __launch_bounds__(256) void prep_kernel(
    const float* __restrict__ feat,
    float* __restrict__ featT,
    const int*   __restrict__ tf_idx,
    const float* __restrict__ W1,
    const float* __restrict__ b1,
    const float* __restrict__ Wm,
    const float* __restrict__ bm,
    const float* __restrict__ Wf,
    const float* __restrict__ bf,
    unsigned* __restrict__ pack)
{
    const int bid = blockIdx.x;
    const int tid = threadIdx.x;
    if (bid < TF_BLOCKS) {
        __shared__ float tile[32][33];
        int t0 = (bid % TF_TX) * 32;
        int b0 = (bid / TF_TX) * 32;
        int tx = tid & 31, ty = tid >> 5;      // (32,8)
        #pragma unroll
        for (int i = 0; i < 32; i += 8) {
            int bb = b0 + ty + i, tt = t0 + tx;
            if (tt < T_) tile[ty + i][tx] = feat[bb * T_ + tt];
        }
        __syncthreads();
        #pragma unroll
        for (int i = 0; i < 32; i += 8) {
            int tt = t0 + ty + i, bb = b0 + tx;
            if (tt < T_) featT[tt * B_ + bb] = tile[tx][ty + i];
        }
        return;
    }
    const int g = bid - TF_BLOCKS;
    const float LOG2E = 1.44269504088896340736f;
    const float SCALE = 1.0507009873554805f;
    const float SL    = SCALE * LOG2E;
    unsigned* rec = pack + (long)g * PSTRIDE;
    for (int j = tid; j < PSTRIDE; j += 256) {
        unsigned u;
        if (j < 16) {
            u = (unsigned)(tf_idx[g * K_ + j] * B_);
        } else if (j < 80) {
            int r = j - 16, k2 = r >> 3, w = r & 7;
            const float* wp = W1 + ((long)g * W_ + w) * K_ + 2 * k2;
            u = pack_h2(LOG2E * wp[0], LOG2E * wp[1]);
        } else if (j < 144) {
            int r = j - 80, d = r >> 5, w2 = (r >> 3) & 3, v = r & 7;
            const float* wp = Wm + (((long)d * G_ + g) * W_ + v) * W_ + 2 * w2;
            u = pack_h2(SL * wp[0], SL * wp[1]);
        } else if (j < 148) {
            int w2 = j - 144;
            const float* wp = Wf + (long)g * W_ + 2 * w2;
            u = pack_h2(SCALE * wp[0], SCALE * wp[1]);
        } else if (j < 156) {
            u = __float_as_uint(LOG2E * b1[g * W_ + (j - 148)]);
        } else if (j < 172) {
            int r = j - 156, d = r >> 3, v = r & 7;
            u = __float_as_uint(LOG2E * bm[((long)d * G_ + g) * W_ + v]);
        } else if (j == 172) {
            u = __float_as_uint(bf[g]);
        } else {
            u = 0;
        }
        rec[j] = u;
    }
}

// outT (G,B) -> out (B,G), both sides coalesced via LDS tile.
__global__ void transpose_out(const float* __restrict__ in,
                              float* __restrict__ outp) {
    __shared__ float tile[32][33];
    int g0 = blockIdx.x * 32;
    int b0 = blockIdx.y * 32;
    int tx = threadIdx.x, ty = threadIdx.y;  // block (32,8)
    #pragma unroll
    for (int i = 0; i < 32; i += 8)
        tile[ty + i][tx] = in[(size_t)(g0 + ty + i) * B_ + b0 + tx];
    __syncthreads();
    #pragma unroll
    for (int i = 0; i < 32; i += 8)
        outp[(size_t)(b0 + ty + i) * G_ + g0 + tx] = tile[tx][ty + i];
}

// ---------- main kernel ----------

// u = log2e * z ; returns selu(z)/scale (scale folded into next layer).
__device__ __forceinline__ float selu_u(float u) {
    const float ALPHA = 1.6732632423543772f;
    const float LN2   = 0.6931471805599453f;
    float e = __builtin_amdgcn_exp2f(u);
    float m = fmaf(ALPHA, e, -ALPHA);
    return fmaf(fmaxf(u, 0.0f), LN2, fminf(m, 0.0f));
}

// 128 threads (2 waves), 1 group/block; thread owns batch rows {2t, 2t+1}.
// Matmuls via v_dot2_f32_f16 (FP16 rate = 2x FP32 on CDNA4): weights are
// uniform f16 pairs (s_load), activations f16 pairs packed with cvt_pkrtz.
__global__ __launch_bounds__(TPB, 6) void decoder_dot2(
    const float* __restrict__ featT,    // (T,B)
    const unsigned* __restrict__ pack,  // (G,PSTRIDE)
    float* __restrict__ outT)           // (G,B)
{
    const int tid = threadIdx.x;
    const int b0  = BPT * tid;
    const int g   = blockIdx.x;
    const float* fb = featT + b0;

    const unsigned* P = pack + (long)g * PSTRIDE;
    const int* idxp   = (const int*)P;          // [0,16): t*B_

    // coalesced float2 gathers (both rows), then pack pairs over k per row
    float2 xg[K_];
    #pragma unroll
    for (int k = 0; k < K_; ++k)
        xg[k] = *(const float2*)(fb + idxp[k]);
    v2h xh0[K_ / 2], xh1[K_ / 2];
    #pragma unroll
    for (int k2 = 0; k2 < K_ / 2; ++k2) {
        xh0[k2] = __builtin_amdgcn_cvt_pkrtz(xg[2 * k2].x, xg[2 * k2 + 1].x);
        xh1[k2] = __builtin_amdgcn_cvt_pkrtz(xg[2 * k2].y, xg[2 * k2 + 1].y);
    }

    // layer 1: acc_r[w] = b1[w] + sum_k2 dot2(w1h[k2][w], xh_r[k2])
    float a0[W_], a1[W_];
    #pragma unroll
    for (int w = 0; w < W_; ++w) {
        float bw = __uint_as_float(P[148 + w]);
        a0[w] = bw; a1[w] = bw;
    }
    #pragma unroll
    for (int k2 = 0; k2 < K_ / 2; ++k2) {
        #pragma unroll
        for (int w = 0; w < W_; ++w) {
            v2h wp = as_v2h(P[16 + 8 * k2 + w]);
            a0[w] = __builtin_amdgcn_fdot2(wp, xh0[k2], a0[w], false);
            a1[w] = __builtin_amdgcn_fdot2(wp, xh1[k2], a1[w], false);
        }
    }
    // selu + pack pairs over w
    v2h hh0[W_ / 2], hh1[W_ / 2];
    #pragma unroll
    for (int w2 = 0; w2 < W_ / 2; ++w2) {
        hh0[w2] = __builtin_amdgcn_cvt_pkrtz(selu_u(a0[2 * w2]), selu_u(a0[2 * w2 + 1]));
        hh1[w2] = __builtin_amdgcn_cvt_pkrtz(selu_u(a1[2 * w2]), selu_u(a1[2 * w2 + 1]));
    }

    // mid layers: m_r[v] = bm[v] + sum_w2 dot2(wmh[d][w2][v], hh_r[w2])
    #pragma unroll
    for (int d = 0; d < D_; ++d) {
        float m0[W_], m1[W_];
        #pragma unroll
        for (int v = 0; v < W_; ++v) {
            float bv = __uint_as_float(P[156 + 8 * d + v]);
            m0[v] = bv; m1[v] = bv;
        }
        #pragma unroll
        for (int w2 = 0; w2 < W_ / 2; ++w2) {
            #pragma unroll
            for (int v = 0; v < W_; ++v) {
                v2h wp = as_v2h(P[80 + 32 * d + 8 * w2 + v]);
                m0[v] = __builtin_amdgcn_fdot2(wp, hh0[w2], m0[v], false);
                m1[v] = __builtin_amdgcn_fdot2(wp, hh1[w2], m1[v], false);
            }
        }
        #pragma unroll
        for (int w2 = 0; w2 < W_ / 2; ++w2) {
            hh0[w2] = __builtin_amdgcn_cvt_pkrtz(selu_u(m0[2 * w2]), selu_u(m0[2 * w2 + 1]));
            hh1[w2] = __builtin_amdgcn_cvt_pkrtz(selu_u(m1[2 * w2]), selu_u(m1[2 * w2 + 1]));
        }
    }

    // final dot
    float bfv = __uint_as_float(P[172]);
    float s0 = bfv, s1 = bfv;
    #pragma unroll
    for (int w2 = 0; w2 < W_ / 2; ++w2) {
        v2h wp = as_v2h(P[144 + w2]);
        s0 = __builtin_amdgcn_fdot2(wp, hh0[w2], s0, false);
        s1 = __builtin_amdgcn_fdot2(wp, hh1[w2], s1, false);
    }

    // full-line coalesced store: 128 threads x 8B = 1KB contiguous per group
    *(float2*)(outT + (size_t)g * B_ + b0) = make_float2(s0, s1);
}

// ---------- fallbacks (small workspace) ----------
#define FGPB 4
__device__ __forceinline__ float selu_f(float x) {
    const float scale = 1.0507009873554805f;
    const float sa    = 1.7580993408473766f;
    float e   = __expf(x);
    float neg = fmaf(sa, e, -sa);
    return x > 0.0f ? scale * x : neg;
}
template<bool TRANSPOSED>
__global__ __launch_bounds__(256) void decoder_kernel(
    const float* __restrict__ featsrc, const int* __restrict__ tf_idx,
    const float* __restrict__ W1, const float* __restrict__ b1,
    const float* __restrict__ Wm, const float* __restrict__ bm,
    const float* __restrict__ Wf, const float* __restrict__ bf,
    float* __restrict__ out)
{
    const int b  = threadIdx.x;
    const int g0 = blockIdx.x * FGPB;
    float res[FGPB];
    #pragma unroll
    for (int gi = 0; gi < FGPB; ++gi) {
        const int g = g0 + gi;
        float xg[K_];
        #pragma unroll
        for (int k = 0; k < K_; ++k) {
            int t = tf_idx[g * K_ + k];
            xg[k] = TRANSPOSED ? featsrc[t * B_ + b] : featsrc[b * T_ + t];
        }
        float h[W_];
        #pragma unroll
        for (int w = 0; w < W_; ++w) {
            float acc = b1[g * W_ + w];
            #pragma unroll
            for (int k = 0; k < K_; ++k)
                acc = fmaf(xg[k], W1[(g * W_ + w) * K_ + k], acc);
            h[w] = selu_f(acc);
        }
        #pragma unroll
        for (int d = 0; d < D_; ++d) {
            const float* wmd = Wm + ((size_t)d * G_ + g) * (W_ * W_);
            const float* bmd = bm + ((size_t)d * G_ + g) * W_;
            float h2[W_];
            #pragma unroll
            for (int v = 0; v < W_; ++v) {
                float acc = bmd[v];
                #pragma unroll
                for (int w = 0; w < W_; ++w)
                    acc = fmaf(h[w], wmd[v * W_ + w], acc);
                h2[v] = selu_f(acc);
            }
            #pragma unroll
            for (int w = 0; w < W_; ++w) h[w] = h2[w];
        }
        float acc = bf[g];
        #pragma unroll
        for (int w = 0; w < W_; ++w)
            acc = fmaf(h[w], Wf[g * W_ + w], acc);
        res[gi] = acc;
    }
    float4* o = (float4*)(out + (size_t)b * G_ + g0);
    o[0] = make_float4(res[0], res[1], res[2], res[3]);
}

extern "C" void kernel_launch(void* const* d_in, const int* in_sizes, int n_in,
                              void* d_out, int out_size, void* d_ws, size_t ws_size,
                              hipStream_t stream) {
    const float* feat   = (const float*)d_in[0];
    const int*   tf_idx = (const int*)  d_in[1];
    const float* W1     = (const float*)d_in[2];
    const float* b1     = (const float*)d_in[3];
    const float* Wm     = (const float*)d_in[4];
    const float* bm     = (const float*)d_in[5];
    const float* Wf     = (const float*)d_in[6];
    const float* bf     = (const float*)d_in[7];
    float* out = (float*)d_out;

    const size_t featT_b = (size_t)T_ * B_ * sizeof(float);           // 1.536 MB
    const size_t pack_b  = (size_t)G_ * PSTRIDE * sizeof(unsigned);   // 14.08 MB
    const size_t outT_b  = (size_t)G_ * B_ * sizeof(float);           // 20.48 MB

    if (ws_size >= featT_b + pack_b + outT_b) {
        float*    featT = (float*)d_ws;
        unsigned* packp = (unsigned*)((char*)d_ws + featT_b);
        float*    outT  = (float*)((char*)d_ws + featT_b + pack_b);

        hipLaunchKernelGGL(prep_kernel, dim3(TF_BLOCKS + G_), dim3(256), 0,
                           stream, feat, featT, tf_idx, W1, b1, Wm, bm, Wf, bf,
                           packp);

        hipLaunchKernelGGL(decoder_dot2, dim3(G_), dim3(TPB), 0,
                           stream, featT, packp, outT);

        hipLaunchKernelGGL(transpose_out, dim3(G_ / 32, B_ / 32), dim3(32, 8), 0,
                           stream, outT, out);
    } else if (ws_size >= featT_b) {
        float* featT = (float*)d_ws;
        hipLaunchKernelGGL(prep_kernel, dim3(TF_BLOCKS), dim3(256), 0,
                           stream, feat, featT, tf_idx, W1, b1, Wm, bm, Wf, bf,
                           (unsigned*)featT /*unused pack*/);
        hipLaunchKernelGGL((decoder_kernel<true>), dim3(G_ / FGPB), dim3(B_), 0,
                           stream, featT, tf_idx, W1, b1, Wm, bm, Wf, bf, out);
    } else {
        hipLaunchKernelGGL((decoder_kernel<false>), dim3(G_ / FGPB), dim3(B_), 0,
                           stream, feat, tf_idx, W1, b1, Wm, bm, Wf, bf, out);
    }
}

// Round 12
// 63.572 us; speedup vs baseline: 1.3475x; 1.1961x over previous
//
#include <hip/hip_runtime.h>
#include <hip/hip_fp16.h>

#define G_ 20000
#define W_ 8
#define K_ 16
#define T_ 1500
#define B_ 256
#define D_ 2

// transpose_feat tiles: ceil(1500/32)=47 x 256/32=8
#define TF_TX 47
#define TF_BLOCKS (TF_TX * 8)

// ---- packed per-GROUP-PAIR record (2 groups), byte offsets ----
// A-matrices are 16x16 f16 row-major [row][k] (512 B each):
//   A1  : rows0-7 = LOG2E*W1_g0[w][k]; rows8-15 = LOG2E*W1_g1  (split in-kernel)
//   AM0 : block-diag SCALE*LOG2E*Wm[0]   (g0 rows/cols 0-7, g1 rows/cols 8-15)
//   AM1 : block-diag SCALE*LOG2E*Wm[1]
//   AF  : row0 = SCALE*Wf_g0 (k0-7); row8 = SCALE*Wf_g1 (k8-15)
// bias frags: 16 f32 in row order (lane reads 4 at q*16)
// idx frags:  16 ints per group = tf_idx<<10 (byte offset into featT rows)
#define REC_BYTES 2432
#define REC_U32   608
#define OFF_A1    0
#define OFF_AM0   512
#define OFF_AM1   1024
#define OFF_AF    1536
#define OFF_B1    2048
#define OFF_BM0   2112
#define OFF_BM1   2176
#define OFF_BF    2240
#define OFF_IDX0  2304
#define OFF_IDX1  2368

using h4  = __attribute__((ext_vector_type(4))) __fp16;
using f4v = __attribute__((ext_vector_type(4))) float;
typedef decltype(__builtin_amdgcn_cvt_pkrtz(0.0f, 0.0f)) v2h;

__device__ __forceinline__ unsigned pack_h2(float lo, float hi) {
    __half l = __float2half(lo), h = __float2half(hi);   // RTE
    return ((unsigned)__half_as_ushort(h) << 16) | __half_as_ushort(l);
}

// ---------- fused prep kernel ----------
// blocks [0, TF_BLOCKS): feat (B,T) -> featT (T,B)
// blocks [TF_BLOCKS, +G_/2): pack ONE group-pair record each.
__global__ __launch_bounds__(256) void prep_kernel(
    const float* __restrict__ feat,
    float* __restrict__ featT,
    const int*   __restrict__ tf_idx,
    const float* __restrict__ W1,
    const float* __restrict__ b1,
    const float* __restrict__ Wm,
    const float* __restrict__ bm,
    const float* __restrict__ Wf,
    const float* __restrict__ bf,
    unsigned* __restrict__ pack)
{
    const int bid = blockIdx.x;
    const int tid = threadIdx.x;
    if (bid < TF_BLOCKS) {
        __shared__ float tile[32][33];
        int t0 = (bid % TF_TX) * 32;
        int b0 = (bid / TF_TX) * 32;
        int tx = tid & 31, ty = tid >> 5;      // (32,8)
        #pragma unroll
        for (int i = 0; i < 32; i += 8) {
            int bb = b0 + ty + i, tt = t0 + tx;
            if (tt < T_) tile[ty + i][tx] = feat[bb * T_ + tt];
        }
        __syncthreads();
        #pragma unroll
        for (int i = 0; i < 32; i += 8) {
            int tt = t0 + ty + i, bb = b0 + tx;
            if (tt < T_) featT[tt * B_ + bb] = tile[tx][ty + i];
        }
        return;
    }
    const int p  = bid - TF_BLOCKS;
    const int g0 = 2 * p, g1 = 2 * p + 1;
    const float LOG2E = 1.44269504088896340736f;
    const float SCALE = 1.0507009873554805f;
    const float SL    = SCALE * LOG2E;
    unsigned* rec = pack + (long)p * REC_U32;
    for (int s = tid; s < REC_U32; s += 256) {
        unsigned u;
        if (s < 128) {                       // A1 (merged W1 pair)
            int row = s >> 3, k0 = (s & 7) * 2;
            const float* wp = (row < 8)
                ? W1 + ((long)g0 * W_ + row) * K_ + k0
                : W1 + ((long)g1 * W_ + (row - 8)) * K_ + k0;
            u = pack_h2(LOG2E * wp[0], LOG2E * wp[1]);
        } else if (s < 384) {                // AM0 / AM1 block-diag
            int r = s - 128, d = r >> 7; r &= 127;
            int row = r >> 3, k0 = (r & 7) * 2;   // k0,k0+1 same side of 8
            float w0 = 0.f, w1 = 0.f;
            if (row < 8 && k0 < 8) {
                const float* wp = Wm + (((long)d * G_ + g0) * W_ + row) * W_ + k0;
                w0 = SL * wp[0]; w1 = SL * wp[1];
            } else if (row >= 8 && k0 >= 8) {
                const float* wp = Wm + (((long)d * G_ + g1) * W_ + (row - 8)) * W_ + (k0 - 8);
                w0 = SL * wp[0]; w1 = SL * wp[1];
            }
            u = pack_h2(w0, w1);
        } else if (s < 512) {                // AF
            int r = s - 384, row = r >> 3, k0 = (r & 7) * 2;
            float w0 = 0.f, w1 = 0.f;
            if (row == 0 && k0 < 8) {
                const float* wp = Wf + (long)g0 * W_ + k0;
                w0 = SCALE * wp[0]; w1 = SCALE * wp[1];
            } else if (row == 8 && k0 >= 8) {
                const float* wp = Wf + (long)g1 * W_ + (k0 - 8);
                w0 = SCALE * wp[0]; w1 = SCALE * wp[1];
            }
            u = pack_h2(w0, w1);
        } else if (s < 528) {                // bias1 (16 f32, row order)
            int row = s - 512;
            float v = (row < 8) ? LOG2E * b1[g0 * W_ + row]
                                : LOG2E * b1[g1 * W_ + row - 8];
            u = __float_as_uint(v);
        } else if (s < 560) {                // biasm d=0,1
            int r = s - 528, d = r >> 4, row = r & 15;
            float v = (row < 8) ? LOG2E * bm[((long)d * G_ + g0) * W_ + row]
                                : LOG2E * bm[((long)d * G_ + g1) * W_ + row - 8];
            u = __float_as_uint(v);
        } else if (s < 576) {                // biasf
            int row = s - 560;
            float v = (row == 0) ? bf[g0] : (row == 8) ? bf[g1] : 0.f;
            u = __float_as_uint(v);
        } else if (s < 592) {                // idx g0 (byte offsets)
            u = (unsigned)(tf_idx[g0 * K_ + (s - 576)] << 10);
        } else {                             // idx g1
            u = (unsigned)(tf_idx[g1 * K_ + (s - 592)] << 10);
        }
        rec[s] = u;
    }
}

// outT (G,B) -> out (B,G), both sides coalesced via LDS tile.
__global__ void transpose_out(const float* __restrict__ in,
                              float* __restrict__ outp) {
    __shared__ float tile[32][33];
    int g0 = blockIdx.x * 32;
    int b0 = blockIdx.y * 32;
    int tx = threadIdx.x, ty = threadIdx.y;  // block (32,8)
    #pragma unroll
    for (int i = 0; i < 32; i += 8)
        tile[ty + i][tx] = in[(size_t)(g0 + ty + i) * B_ + b0 + tx];
    __syncthreads();
    #pragma unroll
    for (int i = 0; i < 32; i += 8)
        outp[(size_t)(b0 + ty + i) * G_ + g0 + tx] = tile[tx][ty + i];
}

// ---------- main MFMA kernel ----------

// u = log2e*z ; returns selu(z)/scale (scale folded into next layer's A).
__device__ __forceinline__ float selu_u(float u) {
    const float ALPHA = 1.6732632423543772f;
    const float LN2   = 0.6931471805599453f;
    float e = __builtin_amdgcn_exp2f(u);
    float m = fmaf(ALPHA, e, -ALPHA);
    return fmaf(fmaxf(u, 0.0f), LN2, fminf(m, 0.0f));
}

__device__ __forceinline__ unsigned cvtpk_u(float a, float b) {
    v2h t = __builtin_amdgcn_cvt_pkrtz(a, b);
    unsigned u; __builtin_memcpy(&u, &t, 4);
    return u;
}

__device__ __forceinline__ f4v mfma16(uint2 a, uint2 b, f4v c) {
    h4 ah, bh;
    __builtin_memcpy(&ah, &a, 8);
    __builtin_memcpy(&bh, &b, 8);
    return __builtin_amdgcn_mfma_f32_16x16x16f16(ah, bh, c, 0, 0, 0);
}

// Block = 256 threads = 4 waves = 2 groups x all 256 batch rows.
// Wave wv owns batch rows [64wv, 64wv+64) = 4 N-tiles of 16.
// Chain identity: D frag (row=(l>>4)*4+r, col=l&15) == next B frag
// (k=(l>>4)*4+j, col=l&15)  ->  selu+cvt in-register between layers.
__global__ __launch_bounds__(256, 4) void decoder_mfma(
    const float* __restrict__ featT,    // (T,B)
    const unsigned* __restrict__ pack,  // (G/2, REC_U32)
    float* __restrict__ outT)           // (G,B)
{
    const int tid  = threadIdx.x;
    const int lane = tid & 63;
    const int wv   = tid >> 6;
    const int p    = blockIdx.x;
    const int g0   = 2 * p, g1 = 2 * p + 1;
    const char* R  = (const char*)(pack + (long)p * REC_U32);
    const char* fc = (const char*)featT;

    const int col  = lane & 15;            // A-row / B-col / C-col
    const int q    = lane >> 4;            // k/row quad
    const int foff = col * 32 + q * 8;     // A frag: 4 f16 at [row=col][k=4q..4q+3]

    uint2 A1  = *(const uint2*)(R + OFF_A1  + foff);
    uint2 AM0 = *(const uint2*)(R + OFF_AM0 + foff);
    uint2 AM1 = *(const uint2*)(R + OFF_AM1 + foff);
    uint2 AF  = *(const uint2*)(R + OFF_AF  + foff);
    const bool rlt8 = col < 8;
    uint2 A1g0, A1g1;                      // split merged W1: disjoint row halves
    A1g0.x = rlt8 ? A1.x : 0u;  A1g0.y = rlt8 ? A1.y : 0u;
    A1g1.x = rlt8 ? 0u : A1.x;  A1g1.y = rlt8 ? 0u : A1.y;

    f4v bias1 = *(const f4v*)(R + OFF_B1  + q * 16);
    f4v bm0   = *(const f4v*)(R + OFF_BM0 + q * 16);
    f4v bm1   = *(const f4v*)(R + OFF_BM1 + q * 16);
    f4v bfin  = *(const f4v*)(R + OFF_BF  + q * 16);
    int4 id0  = *(const int4*)(R + OFF_IDX0 + q * 16);
    int4 id1  = *(const int4*)(R + OFF_IDX1 + q * 16);

    #pragma unroll
    for (int t = 0; t < 4; ++t) {
        const int bb = wv * 64 + t * 16;
        const int vb = (bb + col) * 4;

        // B gathers: lane (col=b, q-quad=k-slice): x[k=4q+j] = featT[t_k][b]
        float x0 = *(const float*)(fc + id0.x + vb);
        float x1 = *(const float*)(fc + id0.y + vb);
        float x2 = *(const float*)(fc + id0.z + vb);
        float x3 = *(const float*)(fc + id0.w + vb);
        float y0 = *(const float*)(fc + id1.x + vb);
        float y1 = *(const float*)(fc + id1.y + vb);
        float y2 = *(const float*)(fc + id1.z + vb);
        float y3 = *(const float*)(fc + id1.w + vb);
        uint2 bg0, bg1;
        bg0.x = cvtpk_u(x0, x1); bg0.y = cvtpk_u(x2, x3);
        bg1.x = cvtpk_u(y0, y1); bg1.y = cvtpk_u(y2, y3);

        // layer 1: two chained mfmas (disjoint A row halves), bias as C-in
        f4v acc = mfma16(A1g0, bg0, bias1);
        acc     = mfma16(A1g1, bg1, acc);

        uint2 bh;
        bh.x = cvtpk_u(selu_u(acc[0]), selu_u(acc[1]));
        bh.y = cvtpk_u(selu_u(acc[2]), selu_u(acc[3]));

        acc  = mfma16(AM0, bh, bm0);
        bh.x = cvtpk_u(selu_u(acc[0]), selu_u(acc[1]));
        bh.y = cvtpk_u(selu_u(acc[2]), selu_u(acc[3]));

        acc  = mfma16(AM1, bh, bm1);
        bh.x = cvtpk_u(selu_u(acc[0]), selu_u(acc[1]));
        bh.y = cvtpk_u(selu_u(acc[2]), selu_u(acc[3]));

        acc = mfma16(AF, bh, bfin);

        // D row 0 (g0) lives in lanes q==0 r=0; row 8 (g1) in q==2 r=0
        if (!(q & 1)) {
            const int gsel = (q & 2) ? g1 : g0;
            outT[(long)gsel * B_ + bb + col] = acc[0];
        }
    }
}

// ---------- fallbacks (small workspace) ----------
#define FGPB 4
__device__ __forceinline__ float selu_f(float x) {
    const float scale = 1.0507009873554805f;
    const float sa    = 1.7580993408473766f;
    float e   = __expf(x);
    float neg = fmaf(sa, e, -sa);
    return x > 0.0f ? scale * x : neg;
}
template<bool TRANSPOSED>
__global__ __launch_bounds__(256) void decoder_kernel(
    const float* __restrict__ featsrc, const int* __restrict__ tf_idx,
    const float* __restrict__ W1, const float* __restrict__ b1,
    const float* __restrict__ Wm, const float* __restrict__ bm,
    const float* __restrict__ Wf, const float* __restrict__ bf,
    float* __restrict__ out)
{
    const int b  = threadIdx.x;
    const int g0 = blockIdx.x * FGPB;
    float res[FGPB];
    #pragma unroll
    for (int gi = 0; gi < FGPB; ++gi) {
        const int g = g0 + gi;
        float xg[K_];
        #pragma unroll
        for (int k = 0; k < K_; ++k) {
            int t = tf_idx[g * K_ + k];
            xg[k] = TRANSPOSED ? featsrc[t * B_ + b] : featsrc[b * T_ + t];
        }
        float h[W_];
        #pragma unroll
        for (int w = 0; w < W_; ++w) {
            float acc = b1[g * W_ + w];
            #pragma unroll
            for (int k = 0; k < K_; ++k)
                acc = fmaf(xg[k], W1[(g * W_ + w) * K_ + k], acc);
            h[w] = selu_f(acc);
        }
        #pragma unroll
        for (int d = 0; d < D_; ++d) {
            const float* wmd = Wm + ((size_t)d * G_ + g) * (W_ * W_);
            const float* bmd = bm + ((size_t)d * G_ + g) * W_;
            float h2[W_];
            #pragma unroll
            for (int v = 0; v < W_; ++v) {
                float acc = bmd[v];
                #pragma unroll
                for (int w = 0; w < W_; ++w)
                    acc = fmaf(h[w], wmd[v * W_ + w], acc);
                h2[v] = selu_f(acc);
            }
            #pragma unroll
            for (int w = 0; w < W_; ++w) h[w] = h2[w];
        }
        float acc = bf[g];
        #pragma unroll
        for (int w = 0; w < W_; ++w)
            acc = fmaf(h[w], Wf[g * W_ + w], acc);
        res[gi] = acc;
    }
    float4* o = (float4*)(out + (size_t)b * G_ + g0);
    o[0] = make_float4(res[0], res[1], res[2], res[3]);
}

extern "C" void kernel_launch(void* const* d_in, const int* in_sizes, int n_in,
                              void* d_out, int out_size, void* d_ws, size_t ws_size,
                              hipStream_t stream) {
    const float* feat   = (const float*)d_in[0];
    const int*   tf_idx = (const int*)  d_in[1];
    const float* W1     = (const float*)d_in[2];
    const float* b1     = (const float*)d_in[3];
    const float* Wm     = (const float*)d_in[4];
    const float* bm     = (const float*)d_in[5];
    const float* Wf     = (const float*)d_in[6];
    const float* bf     = (const float*)d_in[7];
    float* out = (float*)d_out;

    const size_t featT_b = (size_t)T_ * B_ * sizeof(float);          // 1.536 MB
    const size_t pack_b  = (size_t)(G_ / 2) * REC_BYTES;             // 24.32 MB
    const size_t outT_b  = (size_t)G_ * B_ * sizeof(float);          // 20.48 MB

    if (ws_size >= featT_b + pack_b + outT_b) {
        float*    featT = (float*)d_ws;
        unsigned* packp = (unsigned*)((char*)d_ws + featT_b);
        float*    outT  = (float*)((char*)d_ws + featT_b + pack_b);

        hipLaunchKernelGGL(prep_kernel, dim3(TF_BLOCKS + G_ / 2), dim3(256), 0,
                           stream, feat, featT, tf_idx, W1, b1, Wm, bm, Wf, bf,
                           packp);

        hipLaunchKernelGGL(decoder_mfma, dim3(G_ / 2), dim3(256), 0,
                           stream, featT, packp, outT);

        hipLaunchKernelGGL(transpose_out, dim3(G_ / 32, B_ / 32), dim3(32, 8), 0,
                           stream, outT, out);
    } else if (ws_size >= featT_b) {
        float* featT = (float*)d_ws;
        hipLaunchKernelGGL(prep_kernel, dim3(TF_BLOCKS), dim3(256), 0,
                           stream, feat, featT, tf_idx, W1, b1, Wm, bm, Wf, bf,
                           (unsigned*)featT /*unused pack*/);
        hipLaunchKernelGGL((decoder_kernel<true>), dim3(G_ / FGPB), dim3(B_), 0,
                           stream, featT, tf_idx, W1, b1, Wm, bm, Wf, bf, out);
    } else {
        hipLaunchKernelGGL((decoder_kernel<false>), dim3(G_ / FGPB), dim3(B_), 0,
                           stream, feat, tf_idx, W1, b1, Wm, bm, Wf, bf, out);
    }
}